// Round 6
// baseline (139.497 us; speedup 1.0000x reference)
//
#include <hip/hip_runtime.h>

#define B 16
#define P 32768
#define NG 128
#define KTOP 4
#define SAMP 2048                // threshold sample size
#define CAP 1024                 // survivor-list capacity per (b,g); mean ~64

typedef unsigned long long u64;
typedef unsigned int u32;

__device__ __forceinline__ void ceu(u64 &x, u64 &y) {
    u64 a = x, b = y; bool gt = a > b;
    x = gt ? a : b;  y = gt ? b : a;
}
__device__ __forceinline__ void cef(float &x, float &y) {
    float h = fmaxf(x, y), l = fminf(x, y); x = h; y = l;
}

// branchless stable sorted-desc top-4 insert of key x
#define INS4(x, a0, a1, a2, a3)                                   \
    {                                                             \
        bool g0 = (x) > a0, g1 = (x) > a1, g2 = (x) > a2, g3 = (x) > a3; \
        u64 n3 = g2 ? a2 : (g3 ? (x) : a3);                       \
        u64 n2 = g1 ? a1 : (g2 ? (x) : a2);                       \
        u64 n1 = g0 ? a0 : (g1 ? (x) : a1);                       \
        u64 n0 = g0 ? (x) : a0;                                   \
        a0 = n0; a1 = n1; a2 = n2; a3 = n3;                       \
    }

// ---------- kernel 1: per-(b,g) threshold + truth table ----------
// tau = 4th-best IoU over priors [0,SAMP). Sample 4th-best <= full 4th-best,
// so {iou >= tau} is a superset of the true top-4. Writes per-(b,g) 32B row:
// [t0,t1,t2,t3, slope, slope*areaT, areaT, tau] for k_scan's s_load_dwordx8.
__global__ __launch_bounds__(256)
void k_tau(const float* __restrict__ rois, const float* __restrict__ targets,
           float* __restrict__ tbl)
{
    #pragma clang fp contract(off)
    const int blk = blockIdx.x;                 // B*NG = 2048
    const int b = blk >> 7, g = blk & (NG - 1);
    const int tid = threadIdx.x, lane = tid & 63, wv = tid >> 6;

    const float4 t = *(const float4*)(targets + ((size_t)(b * NG + g)) * 4);
    const float areaT = (t.z - t.x) * (t.w - t.y);
    const float4* __restrict__ pv = (const float4*)(rois + ((size_t)(2 * b + 1)) * P * 4);

    __shared__ float sf[4][4];
    float w0 = -1.f, w1 = -1.f, w2 = -1.f, w3 = -1.f;
    #pragma unroll
    for (int it = 0; it < SAMP / 256; ++it) {
        float4 q = pv[it * 256 + tid];
        float ap = (q.z - q.x) * (q.w - q.y);
        float ltx = fmaxf(t.x, q.x), lty = fmaxf(t.y, q.y);
        float rbx = fminf(t.z, q.z), rby = fminf(t.w, q.w);
        float wx = fmaxf(rbx - ltx, 0.0f);
        float wy = fmaxf(rby - lty, 0.0f);
        float inter = wx * wy;
        float iou = inter / ((areaT + ap) - inter);
        float x = iou, hh;
        hh = fmaxf(w0, x); x = fminf(w0, x); w0 = hh;
        hh = fmaxf(w1, x); x = fminf(w1, x); w1 = hh;
        hh = fmaxf(w2, x); x = fminf(w2, x); w2 = hh;
        w3 = fmaxf(w3, x);
    }
    #pragma unroll
    for (int d = 32; d >= 1; d >>= 1) {
        float n0 = __shfl_down(w0, d, 64);
        float n1 = __shfl_down(w1, d, 64);
        float n2 = __shfl_down(w2, d, 64);
        float n3 = __shfl_down(w3, d, 64);
        cef(w0, n3); cef(w1, n2); cef(w2, n1); cef(w3, n0);
        cef(w0, w2); cef(w1, w3); cef(w0, w1); cef(w2, w3);
    }
    if (lane == 0) { sf[wv][0] = w0; sf[wv][1] = w1; sf[wv][2] = w2; sf[wv][3] = w3; }
    __syncthreads();
    if (tid == 0) {
        float m0 = -1.f, m1 = -1.f, m2 = -1.f, m3 = -1.f;
        #pragma unroll
        for (int j = 0; j < 16; ++j) {
            float x = sf[j >> 2][j & 3], hh;
            hh = fmaxf(m0, x); x = fminf(m0, x); m0 = hh;
            hh = fmaxf(m1, x); x = fminf(m1, x); m1 = hh;
            hh = fmaxf(m2, x); x = fminf(m2, x); m2 = hh;
            m3 = fmaxf(m3, x);
        }
        float sl = (m3 / (1.0f + m3)) * (1.0f - 2e-4f);   // conservative shrink >> fp err
        float* dst = tbl + (size_t)blk * 8;
        dst[0] = t.x; dst[1] = t.y; dst[2] = t.z; dst[3] = t.w;
        dst[4] = sl;  dst[5] = sl * areaT; dst[6] = areaT; dst[7] = m3;
    }
}

// ---------- kernel 2: register-resident filtered scan ----------
// LAYOUT FLIP (R5 lesson: four different load-per-iteration bodies all pinned at
// ~45.8us, ~35 issue-slots/eval -> the eval math was never the cost; operand
// delivery was). Here: thread = one PRIOR, held in VGPRs (one coalesced float4
// load, ever). Truth stream is wave-uniform, fed by the SCALAR pipe
// (s_load_dwordx8 of the 32B tbl row; index = loop counter only -> provably
// uniform). Hot iteration = 11 VALU with SGPR operands, ZERO loads, zero
// addressing, zero mask bookkeeping.
// Survivors exit via a side-effecting branch (atomicAdd + store): atomics
// cannot be speculated, so the compiler MUST keep a real branch (the R2
// flattening is structurally impossible). __any gives the wave-level skip;
// the same-address atomic coalesces to one per wave via mbcnt (guide m20).
__global__ __launch_bounds__(256, 8)
void k_scan(const float* __restrict__ rois, const float* __restrict__ tbl,
            u32* __restrict__ cnt, u64* __restrict__ list)
{
    #pragma clang fp contract(off)
    const int blk = blockIdx.x;                 // B * P/256 = 2048
    const int b = blk >> 7, tile = blk & 127;
    const int tid = threadIdx.x;
    const int pidx = (tile << 8) | tid;

    const float4 q = ((const float4*)(rois + ((size_t)(2 * b + 1)) * P * 4))[pidx];
    const float ap = (q.z - q.x) * (q.w - q.y); // same expr as reference area_p
    const float* __restrict__ tb = tbl + (size_t)b * NG * 8;
    const u32 klo = (u32)(~pidx);

    #pragma unroll 8
    for (int g = 0; g < NG; ++g) {
        const float tt0 = tb[g * 8 + 0], tt1 = tb[g * 8 + 1];
        const float tt2 = tb[g * 8 + 2], tt3 = tb[g * 8 + 3];
        const float sl  = tb[g * 8 + 4], cA  = tb[g * 8 + 5];
        const float aT  = tb[g * 8 + 6];
        float ltx = fmaxf(tt0, q.x), lty = fmaxf(tt1, q.y);
        float rbx = fminf(tt2, q.z), rby = fminf(tt3, q.w);
        float wx = fmaxf(rbx - ltx, 0.0f);
        float wy = fmaxf(rby - lty, 0.0f);
        float inter = wx * wy;
        bool pass = inter >= __builtin_fmaf(sl, ap, cA);
        if (__builtin_expect(__any(pass), 0)) {
            if (pass) {
                float iou = inter / ((aT + ap) - inter);   // bit-exact vs reference
                u64 key = ((u64)__float_as_uint(iou) << 32) | klo;
                u32 slot = atomicAdd(&cnt[b * NG + g], 1u);
                if (slot < CAP) list[((size_t)(b * NG + g)) * CAP + slot] = key;
            }
        }
    }
}

// ---------- kernel 3: per-(b,g) top-4 over its survivor list, encode, write ----------
__global__ __launch_bounds__(64)
void k_top(const float* __restrict__ rois, const float* __restrict__ targets,
           const u32* __restrict__ cnt, const u64* __restrict__ list,
           float* __restrict__ out)
{
    #pragma clang fp contract(off)
    const int blk = blockIdx.x;                 // B*NG = 2048
    const int b = blk >> 7, g = blk & (NG - 1);
    const int lane = threadIdx.x;

    const int n = (int)min(cnt[b * NG + g], (u32)CAP);   // >=4 always: sample-best pass
    const u64* __restrict__ src = list + ((size_t)(b * NG + g)) * CAP;

    u64 a0 = 0, a1 = 0, a2 = 0, a3 = 0;
    for (int i = lane; i < n; i += 64) {
        u64 x = src[i];
        INS4(x, a0, a1, a2, a3);
    }
    #pragma unroll
    for (int d = 32; d >= 1; d >>= 1) {
        u64 n0 = __shfl_down(a0, d, 64);
        u64 n1 = __shfl_down(a1, d, 64);
        u64 n2 = __shfl_down(a2, d, 64);
        u64 n3 = __shfl_down(a3, d, 64);
        ceu(a0, n3); ceu(a1, n2); ceu(a2, n1); ceu(a3, n0);
        ceu(a0, a2); ceu(a1, a3); ceu(a0, a1); ceu(a2, a3);
    }
    if (lane == 0) {
        const float4 t = *(const float4*)(targets + ((size_t)(b * NG + g)) * 4);
        const float t0 = t.x, t1 = t.y, t2 = t.z, t3 = t.w;
        const float gw = t2 - t0, gh = t3 - t1;
        const float gcx = (t0 + t2) * 0.5f;
        const float gcy = (t1 + t3) * 0.5f;
        const float4* __restrict__ pv =
            (const float4*)(rois + ((size_t)(2 * b + 1)) * P * 4);
        float4* __restrict__ o4 = (float4*)out;

        u64 ks[KTOP] = {a0, a1, a2, a3};
        #pragma unroll
        for (int k = 0; k < KTOP; ++k) {
            int idx = (int)(~(u32)ks[k]) & (P - 1);
            float4 q = pv[idx];
            float pcx = (q.x + q.z) * 0.5f;
            float pcy = (q.y + q.w) * 0.5f;
            float pw  = q.z - q.x;
            float ph  = q.w - q.y;
            float4 r;
            r.x = (gcx - pcx) / (0.1f * pw);
            r.y = (gcy - pcy) / (0.1f * ph);
            r.z = logf(gw / pw) / 0.2f;
            r.w = logf(gh / ph) / 0.2f;
            o4[((size_t)(b * NG + g)) * KTOP + k] = r;
        }
    }
}

extern "C" void kernel_launch(void* const* d_in, const int* in_sizes, int n_in,
                              void* d_out, int out_size, void* d_ws, size_t ws_size,
                              hipStream_t stream) {
    const float* rois    = (const float*)d_in[0];
    const float* targets = (const float*)d_in[1];
    float* out = (float*)d_out;

    float* tbl = (float*)d_ws;                          // 2048*32B = 64 KB
    u32*   cnt = (u32*)((char*)d_ws + 65536);           // 8 KB
    u64*   list = (u64*)((char*)d_ws + 131072);         // 2048*1024*8B = 16 MB

    hipMemsetAsync(cnt, 0, B * NG * sizeof(u32), stream);
    k_tau <<<dim3(B * NG),       dim3(256), 0, stream>>>(rois, targets, tbl);
    k_scan<<<dim3(B * (P/256)),  dim3(256), 0, stream>>>(rois, tbl, cnt, list);
    k_top <<<dim3(B * NG),       dim3(64),  0, stream>>>(rois, targets, cnt, list, out);
}

// Round 7
// 122.876 us; speedup vs baseline: 1.1353x; 1.1353x over previous
//
#include <hip/hip_runtime.h>

#define B 16
#define P 32768
#define NG 128
#define KTOP 4
#define NT 128                   // prior tiles per batch (256 priors each)
#define SAMP 2048                // threshold sample size
#define CAPL 16                  // LDS survivor-list capacity per (block,g); mean ~0.5

typedef unsigned long long u64;
typedef unsigned int u32;

__device__ __forceinline__ void ceu(u64 &x, u64 &y) {
    u64 a = x, b = y; bool gt = a > b;
    x = gt ? a : b;  y = gt ? b : a;
}
__device__ __forceinline__ void cef(float &x, float &y) {
    float h = fmaxf(x, y), l = fminf(x, y); x = h; y = l;
}

// branchless stable sorted-desc top-4 insert of key x
#define INS4(x, a0, a1, a2, a3)                                   \
    {                                                             \
        bool g0 = (x) > a0, g1 = (x) > a1, g2 = (x) > a2, g3 = (x) > a3; \
        u64 n3 = g2 ? a2 : (g3 ? (x) : a3);                       \
        u64 n2 = g1 ? a1 : (g2 ? (x) : a2);                       \
        u64 n1 = g0 ? a0 : (g1 ? (x) : a1);                       \
        u64 n0 = g0 ? (x) : a0;                                   \
        a0 = n0; a1 = n1; a2 = n2; a3 = n3;                       \
    }

// ---------- kernel 1: per-(b,g) threshold + truth table ----------
// tau = 4th-best IoU over priors [0,SAMP). Sample 4th-best <= full 4th-best,
// so {iou >= tau} is a superset of the true top-4. Writes per-(b,g) 32B row:
// [t0,t1,t2,t3, slope, pad, areaT, tau] for k_scan's s_load_dwordx8.
__global__ __launch_bounds__(256)
void k_tau(const float* __restrict__ rois, const float* __restrict__ targets,
           float* __restrict__ tbl)
{
    #pragma clang fp contract(off)
    const int blk = blockIdx.x;                 // B*NG = 2048
    const int b = blk >> 7, g = blk & (NG - 1);
    const int tid = threadIdx.x, lane = tid & 63, wv = tid >> 6;

    const float4 t = *(const float4*)(targets + ((size_t)(b * NG + g)) * 4);
    const float areaT = (t.z - t.x) * (t.w - t.y);
    const float4* __restrict__ pv = (const float4*)(rois + ((size_t)(2 * b + 1)) * P * 4);

    __shared__ float sf[4][4];
    float w0 = -1.f, w1 = -1.f, w2 = -1.f, w3 = -1.f;
    #pragma unroll
    for (int it = 0; it < SAMP / 256; ++it) {
        float4 q = pv[it * 256 + tid];
        float ap = (q.z - q.x) * (q.w - q.y);
        float ltx = fmaxf(t.x, q.x), lty = fmaxf(t.y, q.y);
        float rbx = fminf(t.z, q.z), rby = fminf(t.w, q.w);
        float wx = fmaxf(rbx - ltx, 0.0f);
        float wy = fmaxf(rby - lty, 0.0f);
        float inter = wx * wy;
        float iou = inter / ((areaT + ap) - inter);
        float x = iou, hh;
        hh = fmaxf(w0, x); x = fminf(w0, x); w0 = hh;
        hh = fmaxf(w1, x); x = fminf(w1, x); w1 = hh;
        hh = fmaxf(w2, x); x = fminf(w2, x); w2 = hh;
        w3 = fmaxf(w3, x);
    }
    #pragma unroll
    for (int d = 32; d >= 1; d >>= 1) {
        float n0 = __shfl_down(w0, d, 64);
        float n1 = __shfl_down(w1, d, 64);
        float n2 = __shfl_down(w2, d, 64);
        float n3 = __shfl_down(w3, d, 64);
        cef(w0, n3); cef(w1, n2); cef(w2, n1); cef(w3, n0);
        cef(w0, w2); cef(w1, w3); cef(w0, w1); cef(w2, w3);
    }
    if (lane == 0) { sf[wv][0] = w0; sf[wv][1] = w1; sf[wv][2] = w2; sf[wv][3] = w3; }
    __syncthreads();
    if (tid == 0) {
        float m0 = -1.f, m1 = -1.f, m2 = -1.f, m3 = -1.f;
        #pragma unroll
        for (int j = 0; j < 16; ++j) {
            float x = sf[j >> 2][j & 3], hh;
            hh = fmaxf(m0, x); x = fminf(m0, x); m0 = hh;
            hh = fmaxf(m1, x); x = fminf(m1, x); m1 = hh;
            hh = fmaxf(m2, x); x = fminf(m2, x); m2 = hh;
            m3 = fmaxf(m3, x);
        }
        float sl = (m3 / (1.0f + m3)) * (1.0f - 2e-4f);   // conservative shrink >> fp err
        float* dst = tbl + (size_t)blk * 8;
        dst[0] = t.x; dst[1] = t.y; dst[2] = t.z; dst[3] = t.w;
        dst[4] = sl;  dst[5] = 0.0f; dst[6] = areaT; dst[7] = m3;
    }
}

// ---------- kernel 2: register-resident scan, LDS survivor lists ----------
// Thread = one PRIOR (float4 in VGPRs, loaded once, coalesced). Truth stream is
// wave-uniform via the SCALAR pipe (s_load_dwordx8 of the 32B tbl row; R6
// verified the promotion fires: VGPR=8/SGPR=32). Hot iter = 12 VALU, all
// single-SGPR-operand legal, zero vector loads.
// R6 lesson: the global atomicAdd-with-return added an L2 round-trip stall per
// survivor (~131K of them) -> 62us at 47% VALUBusy. Survivors now push to an
// LDS list (LDS atomic ~30cy, no L2 trip); per-g lists reduced IN-BLOCK, one
// 32B partial per (block,g); k_top merges the 128 partials (proven ~2us).
// Overflow (P ~1e-18, and the tau=0 degenerate case): thread g rescans this
// block's 256 priors exactly -> correctness never depends on the cap.
__global__ __launch_bounds__(256, 8)
void k_scan(const float* __restrict__ rois, const float* __restrict__ tbl,
            u64* __restrict__ part)
{
    #pragma clang fp contract(off)
    const int blk = blockIdx.x;                 // B * NT = 2048
    const int b = blk >> 7, tile = blk & (NT - 1);
    const int tid = threadIdx.x;
    const int pidx = (tile << 8) | tid;

    __shared__ u32 lcnt[NG];                    // 512 B
    __shared__ u64 llist[NG][CAPL];             // 16 KB

    for (int i = tid; i < NG; i += 256) lcnt[i] = 0;

    const float4* __restrict__ pvb = (const float4*)(rois + ((size_t)(2 * b + 1)) * P * 4);
    const float4 q = pvb[pidx];
    const float ap = (q.z - q.x) * (q.w - q.y); // same expr as reference area_p
    const float* __restrict__ tb = tbl + (size_t)b * NG * 8;
    const u32 klo = (u32)(~pidx);
    __syncthreads();

    #pragma unroll 4
    for (int g = 0; g < NG; ++g) {
        const float tt0 = tb[g * 8 + 0], tt1 = tb[g * 8 + 1];
        const float tt2 = tb[g * 8 + 2], tt3 = tb[g * 8 + 3];
        const float sl  = tb[g * 8 + 4], aT  = tb[g * 8 + 6];
        float ltx = fmaxf(tt0, q.x), lty = fmaxf(tt1, q.y);
        float rbx = fminf(tt2, q.z), rby = fminf(tt3, q.w);
        float wx = fmaxf(rbx - ltx, 0.0f);
        float wy = fmaxf(rby - lty, 0.0f);
        float inter = wx * wy;
        float sum = aT + ap;                    // reused by exact denom (same op order)
        bool pass = inter >= sl * sum;
        if (__builtin_expect(__any(pass), 0)) {
            if (pass) {
                float iou = inter / (sum - inter);     // == inter/((areaT+ap)-inter)
                u64 key = ((u64)__float_as_uint(iou) << 32) | klo;
                u32 slot = atomicAdd(&lcnt[g], 1u);    // LDS atomic: no L2 trip
                if (slot < CAPL) llist[g][slot] = key;
            }
        }
    }
    __syncthreads();

    // in-block reduction: thread g -> sorted top-4 partial for (b,tile,g)
    if (tid < NG) {
        const int g = tid;
        u64 f0 = 0, f1 = 0, f2 = 0, f3 = 0;
        const u32 n = lcnt[g];
        if (__builtin_expect(n > CAPL, 0)) {
            // exact fallback: rescan this block's 256 priors for truth g
            const float tt0 = tb[g * 8 + 0], tt1 = tb[g * 8 + 1];
            const float tt2 = tb[g * 8 + 2], tt3 = tb[g * 8 + 3];
            const float sl  = tb[g * 8 + 4], aT  = tb[g * 8 + 6];
            for (int i = 0; i < 256; ++i) {
                float4 qq = pvb[(tile << 8) | i];
                float app = (qq.z - qq.x) * (qq.w - qq.y);
                float ltx = fmaxf(tt0, qq.x), lty = fmaxf(tt1, qq.y);
                float rbx = fminf(tt2, qq.z), rby = fminf(tt3, qq.w);
                float wx = fmaxf(rbx - ltx, 0.0f);
                float wy = fmaxf(rby - lty, 0.0f);
                float inter = wx * wy;
                float sum = aT + app;
                if (inter >= sl * sum) {
                    float iou = inter / (sum - inter);
                    u64 x = ((u64)__float_as_uint(iou) << 32) | (u32)(~((tile << 8) | i));
                    INS4(x, f0, f1, f2, f3);
                }
            }
        } else {
            for (u32 i = 0; i < n; ++i) {
                u64 x = llist[g][i];
                INS4(x, f0, f1, f2, f3);
            }
        }
        u64* dst = part + (((size_t)b * NT + tile) * NG + g) * KTOP;
        dst[0] = f0; dst[1] = f1; dst[2] = f2; dst[3] = f3;
    }
}

// ---------- kernel 3: merge 128 tile-partials per (b,g), encode, write ----------
__global__ __launch_bounds__(64)
void k_top(const float* __restrict__ rois, const float* __restrict__ targets,
           const u64* __restrict__ part, float* __restrict__ out)
{
    #pragma clang fp contract(off)
    const int blk = blockIdx.x;                 // B*NG = 2048
    const int b = blk >> 7, g = blk & (NG - 1);
    const int lane = threadIdx.x;               // lane = tile index (x2)

    const u64* __restrict__ s0 = part + (((size_t)b * NT + lane) * NG + g) * KTOP;
    const u64* __restrict__ s1 = part + (((size_t)b * NT + lane + 64) * NG + g) * KTOP;
    u64 a0 = s0[0], a1 = s0[1], a2 = s0[2], a3 = s0[3];
    u64 b0 = s1[0], b1 = s1[1], b2 = s1[2], b3 = s1[3];
    ceu(a0, b3); ceu(a1, b2); ceu(a2, b1); ceu(a3, b0);
    ceu(a0, a2); ceu(a1, a3); ceu(a0, a1); ceu(a2, a3);
    #pragma unroll
    for (int d = 32; d >= 1; d >>= 1) {
        u64 n0 = __shfl_down(a0, d, 64);
        u64 n1 = __shfl_down(a1, d, 64);
        u64 n2 = __shfl_down(a2, d, 64);
        u64 n3 = __shfl_down(a3, d, 64);
        ceu(a0, n3); ceu(a1, n2); ceu(a2, n1); ceu(a3, n0);
        ceu(a0, a2); ceu(a1, a3); ceu(a0, a1); ceu(a2, a3);
    }
    if (lane == 0) {
        const float4 t = *(const float4*)(targets + ((size_t)(b * NG + g)) * 4);
        const float t0 = t.x, t1 = t.y, t2 = t.z, t3 = t.w;
        const float gw = t2 - t0, gh = t3 - t1;
        const float gcx = (t0 + t2) * 0.5f;
        const float gcy = (t1 + t3) * 0.5f;
        const float4* __restrict__ pv =
            (const float4*)(rois + ((size_t)(2 * b + 1)) * P * 4);
        float4* __restrict__ o4 = (float4*)out;

        u64 ks[KTOP] = {a0, a1, a2, a3};
        #pragma unroll
        for (int k = 0; k < KTOP; ++k) {
            int idx = (int)(~(u32)ks[k]) & (P - 1);
            float4 q = pv[idx];
            float pcx = (q.x + q.z) * 0.5f;
            float pcy = (q.y + q.w) * 0.5f;
            float pw  = q.z - q.x;
            float ph  = q.w - q.y;
            float4 r;
            r.x = (gcx - pcx) / (0.1f * pw);
            r.y = (gcy - pcy) / (0.1f * ph);
            r.z = logf(gw / pw) / 0.2f;
            r.w = logf(gh / ph) / 0.2f;
            o4[((size_t)(b * NG + g)) * KTOP + k] = r;
        }
    }
}

extern "C" void kernel_launch(void* const* d_in, const int* in_sizes, int n_in,
                              void* d_out, int out_size, void* d_ws, size_t ws_size,
                              hipStream_t stream) {
    const float* rois    = (const float*)d_in[0];
    const float* targets = (const float*)d_in[1];
    float* out = (float*)d_out;

    float* tbl  = (float*)d_ws;                         // 2048*32B = 64 KB
    u64*   part = (u64*)((char*)d_ws + 65536);          // 16*128*128*32B = 8 MB

    k_tau <<<dim3(B * NG), dim3(256), 0, stream>>>(rois, targets, tbl);
    k_scan<<<dim3(B * NT), dim3(256), 0, stream>>>(rois, tbl, part);
    k_top <<<dim3(B * NG), dim3(64),  0, stream>>>(rois, targets, part, out);
}

// Round 8
// 111.439 us; speedup vs baseline: 1.2518x; 1.1026x over previous
//
#include <hip/hip_runtime.h>

#define B 16
#define P 32768
#define NG 128
#define KTOP 4
#define NTB 64                   // prior tiles per batch (512 priors each, 2/thread)
#define SAMP 2048                // threshold sample size
#define CAPL 16                  // LDS survivor-list cap per (block,g); mean ~1.0

typedef unsigned long long u64;
typedef unsigned int u32;

__device__ __forceinline__ void ceu(u64 &x, u64 &y) {
    u64 a = x, b = y; bool gt = a > b;
    x = gt ? a : b;  y = gt ? b : a;
}
__device__ __forceinline__ void cef(float &x, float &y) {
    float h = fmaxf(x, y), l = fminf(x, y); x = h; y = l;
}

// branchless stable sorted-desc top-4 insert of key x
#define INS4(x, a0, a1, a2, a3)                                   \
    {                                                             \
        bool g0 = (x) > a0, g1 = (x) > a1, g2 = (x) > a2, g3 = (x) > a3; \
        u64 n3 = g2 ? a2 : (g3 ? (x) : a3);                       \
        u64 n2 = g1 ? a1 : (g2 ? (x) : a2);                       \
        u64 n1 = g0 ? a0 : (g1 ? (x) : a1);                       \
        u64 n0 = g0 ? (x) : a0;                                   \
        a0 = n0; a1 = n1; a2 = n2; a3 = n3;                       \
    }

// ---------- kernel 1: per-(b,g) threshold + truth table ----------
// tau = 4th-best IoU over priors [0,SAMP). Sample 4th-best <= full 4th-best,
// so {iou >= tau} is a superset of the true top-4. Writes per-(b,g) 32B row:
// [t0,t1,t2,t3, slope, slope*areaT, areaT, tau] for k_scan's s_load_dwordx8.
__global__ __launch_bounds__(256)
void k_tau(const float* __restrict__ rois, const float* __restrict__ targets,
           float* __restrict__ tbl)
{
    #pragma clang fp contract(off)
    const int blk = blockIdx.x;                 // B*NG = 2048
    const int b = blk >> 7, g = blk & (NG - 1);
    const int tid = threadIdx.x, lane = tid & 63, wv = tid >> 6;

    const float4 t = *(const float4*)(targets + ((size_t)(b * NG + g)) * 4);
    const float areaT = (t.z - t.x) * (t.w - t.y);
    const float4* __restrict__ pv = (const float4*)(rois + ((size_t)(2 * b + 1)) * P * 4);

    __shared__ float sf[4][4];
    float w0 = -1.f, w1 = -1.f, w2 = -1.f, w3 = -1.f;
    #pragma unroll
    for (int it = 0; it < SAMP / 256; ++it) {
        float4 q = pv[it * 256 + tid];
        float ap = (q.z - q.x) * (q.w - q.y);
        float ltx = fmaxf(t.x, q.x), lty = fmaxf(t.y, q.y);
        float rbx = fminf(t.z, q.z), rby = fminf(t.w, q.w);
        float wx = fmaxf(rbx - ltx, 0.0f);
        float wy = fmaxf(rby - lty, 0.0f);
        float inter = wx * wy;
        float iou = inter / ((areaT + ap) - inter);
        float x = iou, hh;
        hh = fmaxf(w0, x); x = fminf(w0, x); w0 = hh;
        hh = fmaxf(w1, x); x = fminf(w1, x); w1 = hh;
        hh = fmaxf(w2, x); x = fminf(w2, x); w2 = hh;
        w3 = fmaxf(w3, x);
    }
    #pragma unroll
    for (int d = 32; d >= 1; d >>= 1) {
        float n0 = __shfl_down(w0, d, 64);
        float n1 = __shfl_down(w1, d, 64);
        float n2 = __shfl_down(w2, d, 64);
        float n3 = __shfl_down(w3, d, 64);
        cef(w0, n3); cef(w1, n2); cef(w2, n1); cef(w3, n0);
        cef(w0, w2); cef(w1, w3); cef(w0, w1); cef(w2, w3);
    }
    if (lane == 0) { sf[wv][0] = w0; sf[wv][1] = w1; sf[wv][2] = w2; sf[wv][3] = w3; }
    __syncthreads();
    if (tid == 0) {
        float m0 = -1.f, m1 = -1.f, m2 = -1.f, m3 = -1.f;
        #pragma unroll
        for (int j = 0; j < 16; ++j) {
            float x = sf[j >> 2][j & 3], hh;
            hh = fmaxf(m0, x); x = fminf(m0, x); m0 = hh;
            hh = fmaxf(m1, x); x = fminf(m1, x); m1 = hh;
            hh = fmaxf(m2, x); x = fminf(m2, x); m2 = hh;
            m3 = fmaxf(m3, x);
        }
        float sl = (m3 / (1.0f + m3)) * (1.0f - 2e-4f);   // conservative shrink >> fp err
        float* dst = tbl + (size_t)blk * 8;
        dst[0] = t.x; dst[1] = t.y; dst[2] = t.z; dst[3] = t.w;
        dst[4] = sl;  dst[5] = sl * areaT; dst[6] = areaT; dst[7] = m3;
    }
}

// ---------- kernel 2: register-resident scan, 2 priors/thread ----------
// R7 invariant: five different loop bodies all pinned at ~45us = ~105 cy per
// wave-ITERATION. Real VALU work is only ~30 cy of that; the rest is
// per-iteration fixed cost (s_load lgkmcnt wait, v_cmp->vcc->s_cbranch hazard,
// loop control). Fix: 2 priors per thread -> 128 evals share one iteration's
// fixed costs (one truth-row s_load, ONE __any branch, one loop step).
// Per-eval test is 11 VALU: 2 max, 2 min, 2 sub, 2 clamp, mul, fma(sl,ap,cA),
// cmp  (cA = sl*areaT from the table; rare path recomputes sum = aT+ap so the
// accepted IoU keeps the reference op order bit-exactly).
// Survivors push to LDS lists (R7: no L2 round-trip); per-g thread reduces to
// one 32B partial; overflow/tau=0 fallback rescans the block's 512 priors.
__global__ __launch_bounds__(256, 8)
void k_scan(const float* __restrict__ rois, const float* __restrict__ tbl,
            u64* __restrict__ part)
{
    #pragma clang fp contract(off)
    const int blk = blockIdx.x;                 // B * NTB = 1024
    const int b = blk >> 6, tile = blk & (NTB - 1);
    const int tid = threadIdx.x;
    const int p0 = (tile << 9) | tid;           // prior 0
    const int p1 = p0 + 256;                    // prior 1

    __shared__ u32 lcnt[NG];                    // 512 B
    __shared__ u64 llist[NG][CAPL];             // 16 KB

    for (int i = tid; i < NG; i += 256) lcnt[i] = 0;

    const float4* __restrict__ pvb = (const float4*)(rois + ((size_t)(2 * b + 1)) * P * 4);
    const float4 q0 = pvb[p0];
    const float4 q1 = pvb[p1];
    const float ap0 = (q0.z - q0.x) * (q0.w - q0.y);   // same expr as reference area_p
    const float ap1 = (q1.z - q1.x) * (q1.w - q1.y);
    const float* __restrict__ tb = tbl + (size_t)b * NG * 8;
    const u32 klo0 = (u32)(~p0), klo1 = (u32)(~p1);
    __syncthreads();

    #pragma unroll 4
    for (int g = 0; g < NG; ++g) {
        const float tt0 = tb[g * 8 + 0], tt1 = tb[g * 8 + 1];
        const float tt2 = tb[g * 8 + 2], tt3 = tb[g * 8 + 3];
        const float sl  = tb[g * 8 + 4], cA  = tb[g * 8 + 5];
        const float aT  = tb[g * 8 + 6];

        float lx0 = fmaxf(tt0, q0.x), ly0 = fmaxf(tt1, q0.y);
        float rx0 = fminf(tt2, q0.z), ry0 = fminf(tt3, q0.w);
        float wx0 = fmaxf(rx0 - lx0, 0.0f);
        float wy0 = fmaxf(ry0 - ly0, 0.0f);
        float in0 = wx0 * wy0;
        bool pa0 = in0 >= __builtin_fmaf(sl, ap0, cA);

        float lx1 = fmaxf(tt0, q1.x), ly1 = fmaxf(tt1, q1.y);
        float rx1 = fminf(tt2, q1.z), ry1 = fminf(tt3, q1.w);
        float wx1 = fmaxf(rx1 - lx1, 0.0f);
        float wy1 = fmaxf(ry1 - ly1, 0.0f);
        float in1 = wx1 * wy1;
        bool pa1 = in1 >= __builtin_fmaf(sl, ap1, cA);

        if (__builtin_expect(__any(pa0 | pa1), 0)) {
            if (pa0) {
                float sum = aT + ap0;
                float iou = in0 / (sum - in0);         // bit-exact vs reference
                u64 key = ((u64)__float_as_uint(iou) << 32) | klo0;
                u32 slot = atomicAdd(&lcnt[g], 1u);    // LDS atomic: no L2 trip
                if (slot < CAPL) llist[g][slot] = key;
            }
            if (pa1) {
                float sum = aT + ap1;
                float iou = in1 / (sum - in1);
                u64 key = ((u64)__float_as_uint(iou) << 32) | klo1;
                u32 slot = atomicAdd(&lcnt[g], 1u);
                if (slot < CAPL) llist[g][slot] = key;
            }
        }
    }
    __syncthreads();

    // in-block reduction: thread g -> sorted top-4 partial for (b,tile,g)
    if (tid < NG) {
        const int g = tid;
        u64 f0 = 0, f1 = 0, f2 = 0, f3 = 0;
        const u32 n = lcnt[g];
        if (__builtin_expect(n > CAPL, 0)) {
            // exact fallback: rescan this block's 512 priors for truth g
            const float tt0 = tb[g * 8 + 0], tt1 = tb[g * 8 + 1];
            const float tt2 = tb[g * 8 + 2], tt3 = tb[g * 8 + 3];
            const float sl  = tb[g * 8 + 4], cA  = tb[g * 8 + 5];
            const float aT  = tb[g * 8 + 6];
            for (int i = 0; i < 512; ++i) {
                int pi = (tile << 9) | i;
                float4 qq = pvb[pi];
                float app = (qq.z - qq.x) * (qq.w - qq.y);
                float ltx = fmaxf(tt0, qq.x), lty = fmaxf(tt1, qq.y);
                float rbx = fminf(tt2, qq.z), rby = fminf(tt3, qq.w);
                float wx = fmaxf(rbx - ltx, 0.0f);
                float wy = fmaxf(rby - lty, 0.0f);
                float inter = wx * wy;
                if (inter >= __builtin_fmaf(sl, app, cA)) {
                    float sum = aT + app;
                    float iou = inter / (sum - inter);
                    u64 x = ((u64)__float_as_uint(iou) << 32) | (u32)(~pi);
                    INS4(x, f0, f1, f2, f3);
                }
            }
        } else {
            for (u32 i = 0; i < n; ++i) {
                u64 x = llist[g][i];
                INS4(x, f0, f1, f2, f3);
            }
        }
        u64* dst = part + (((size_t)b * NTB + tile) * NG + g) * KTOP;
        dst[0] = f0; dst[1] = f1; dst[2] = f2; dst[3] = f3;
    }
}

// ---------- kernel 3: merge 64 tile-partials per (b,g) (1/lane), encode, write ----------
__global__ __launch_bounds__(64)
void k_top(const float* __restrict__ rois, const float* __restrict__ targets,
           const u64* __restrict__ part, float* __restrict__ out)
{
    #pragma clang fp contract(off)
    const int blk = blockIdx.x;                 // B*NG = 2048
    const int b = blk >> 7, g = blk & (NG - 1);
    const int lane = threadIdx.x;               // lane = tile index

    const u64* __restrict__ s0 = part + (((size_t)b * NTB + lane) * NG + g) * KTOP;
    u64 a0 = s0[0], a1 = s0[1], a2 = s0[2], a3 = s0[3];
    #pragma unroll
    for (int d = 32; d >= 1; d >>= 1) {
        u64 n0 = __shfl_down(a0, d, 64);
        u64 n1 = __shfl_down(a1, d, 64);
        u64 n2 = __shfl_down(a2, d, 64);
        u64 n3 = __shfl_down(a3, d, 64);
        ceu(a0, n3); ceu(a1, n2); ceu(a2, n1); ceu(a3, n0);
        ceu(a0, a2); ceu(a1, a3); ceu(a0, a1); ceu(a2, a3);
    }
    if (lane == 0) {
        const float4 t = *(const float4*)(targets + ((size_t)(b * NG + g)) * 4);
        const float t0 = t.x, t1 = t.y, t2 = t.z, t3 = t.w;
        const float gw = t2 - t0, gh = t3 - t1;
        const float gcx = (t0 + t2) * 0.5f;
        const float gcy = (t1 + t3) * 0.5f;
        const float4* __restrict__ pv =
            (const float4*)(rois + ((size_t)(2 * b + 1)) * P * 4);
        float4* __restrict__ o4 = (float4*)out;

        u64 ks[KTOP] = {a0, a1, a2, a3};
        #pragma unroll
        for (int k = 0; k < KTOP; ++k) {
            int idx = (int)(~(u32)ks[k]) & (P - 1);
            float4 q = pv[idx];
            float pcx = (q.x + q.z) * 0.5f;
            float pcy = (q.y + q.w) * 0.5f;
            float pw  = q.z - q.x;
            float ph  = q.w - q.y;
            float4 r;
            r.x = (gcx - pcx) / (0.1f * pw);
            r.y = (gcy - pcy) / (0.1f * ph);
            r.z = logf(gw / pw) / 0.2f;
            r.w = logf(gh / ph) / 0.2f;
            o4[((size_t)(b * NG + g)) * KTOP + k] = r;
        }
    }
}

extern "C" void kernel_launch(void* const* d_in, const int* in_sizes, int n_in,
                              void* d_out, int out_size, void* d_ws, size_t ws_size,
                              hipStream_t stream) {
    const float* rois    = (const float*)d_in[0];
    const float* targets = (const float*)d_in[1];
    float* out = (float*)d_out;

    float* tbl  = (float*)d_ws;                         // 2048*32B = 64 KB
    u64*   part = (u64*)((char*)d_ws + 65536);          // 16*64*128*32B = 4 MB

    k_tau <<<dim3(B * NG),  dim3(256), 0, stream>>>(rois, targets, tbl);
    k_scan<<<dim3(B * NTB), dim3(256), 0, stream>>>(rois, tbl, part);
    k_top <<<dim3(B * NG),  dim3(64),  0, stream>>>(rois, targets, part, out);
}